// Round 1
// baseline (780.044 us; speedup 1.0000x reference)
//
#include <hip/hip_runtime.h>

// ---------------------------------------------------------------------------
// Fused kernel for Model_84464826843698 on gfx950.
// B=4, Cin=128, N=16384, K=16, MID=64, OUT=128, SHARE=8, PT=10
// One block = 8 positions (n), 512 threads (8 waves). All stages fused in LDS.
// ---------------------------------------------------------------------------

typedef __attribute__((ext_vector_type(8))) short bf16x8;
typedef __attribute__((ext_vector_type(4))) float f32x4;
typedef __attribute__((ext_vector_type(4))) float float4v;
typedef __attribute__((ext_vector_type(4))) unsigned short ushort4v;
typedef __attribute__((ext_vector_type(8))) unsigned short ushort8v;

#define MFMA(a, b, c) __builtin_amdgcn_mfma_f32_16x16x32_bf16((a), (b), (c), 0, 0, 0)

#define TP 8

// LDS byte offsets (all 16B aligned). Total 128896 B.
#define OFF_F 0         // F   [8 pos][16 kslot][272B: 128 ch bf16 + pad]    (34944), dead after ph1
#define OFF_X2 0        // X2  [8 pos][16 kslot][144B: 64 ch]                (18432), reuses F
#define OFF_X3 18432    // X3  [8 pos][2064B: 1024 c' bf16 + pad]            (16512), reuses F
#define OFF_XN 34944    // XN  [8][16][272B]                                 (34944)
#define OFF_P 69888     // P   [8][16][80B: 32 p bf16 (>=10 zero) + pad]     (10368)
#define OFF_H1 80256    // H1  [8][16][144B]                                 (18432), dead after ph3
#define OFF_XFS 80256   // XFS [8][2064B]                                    (16512), reuses H1
#define OFF_PTF 98688   // PTF [8][16][144B]                                 (18432)
#define OFF_X1 117120   // x1  [8 pos][64] f32                               (2048)
#define OFF_HP 119168   // h partials [8 wave][64] f32                       (2048)
#define OFF_HB 121216   // h   [8 j][8 pos] f32                              (256)
#define OFF_WS 121472   // softmax w [8 pos][8 j2][16 k] f32                 (4096)
#define OFF_OM 125568   // om  [8 pos][144B: 64 m bf16 + pad]                (1152)
#define OFF_XC 126720   // xcol(identity) [8 pos][272B: 128 o bf16 + pad]    (2176)
#define SMEM_BYTES 128896

__device__ __forceinline__ unsigned short f2bf(float f) {
    union { float f; unsigned u; } v;
    v.f = f;
    unsigned r = (v.u + 0x7FFFu + ((v.u >> 16) & 1u)) >> 16;
    return (unsigned short)r;
}

__device__ __forceinline__ float bf2f(unsigned short u) {
    union { unsigned u; float f; } v;
    v.u = ((unsigned)u) << 16;
    return v.f;
}

// Load 8 consecutive fp32 weights -> bf16x8 A-fragment (32B-aligned source).
__device__ __forceinline__ bf16x8 ldw_bf8(const float* p) {
    float4v a = *(const float4v*)p;
    float4v c = *(const float4v*)(p + 4);
    bf16x8 r;
    r[0] = (short)f2bf(a[0]); r[1] = (short)f2bf(a[1]);
    r[2] = (short)f2bf(a[2]); r[3] = (short)f2bf(a[3]);
    r[4] = (short)f2bf(c[0]); r[5] = (short)f2bf(c[1]);
    r[6] = (short)f2bf(c[2]); r[7] = (short)f2bf(c[3]);
    return r;
}

__global__ __launch_bounds__(512, 2)
void fused_model_kernel(const float* __restrict__ feats, const float* __restrict__ ppfs,
                        const float* __restrict__ w0, const float* __restrict__ b0,
                        const float* __restrict__ w1, const float* __restrict__ b1,
                        const float* __restrict__ w2, const float* __restrict__ b2,
                        const float* __restrict__ w3, const float* __restrict__ b3,
                        const float* __restrict__ cw1, const float* __restrict__ cw2,
                        const float* __restrict__ cb2, const float* __restrict__ wo,
                        const float* __restrict__ bo, const float* __restrict__ p1,
                        const float* __restrict__ p2, float* __restrict__ out) {
    extern __shared__ char smem[];
    const int tid = threadIdx.x;
    const int W = tid >> 6;       // wave 0..7
    const int lane = tid & 63;
    const int kk = lane & 15;     // MFMA col / A-row index
    const int g = lane >> 4;      // MFMA k-group
    const int bid = blockIdx.x;
    const int b = bid >> 11;            // 2048 n-tiles per batch
    const int n0 = (bid & 2047) * TP;

    // ---------------- Phase 0: stage feats + ppfs into LDS (fp32 -> bf16) ---
    for (int it = 0; it < 8; ++it) {
        int u = tid + it * 512;                 // 4096 units: [pos][ci][kq]
        int kq = u & 3, ci = (u >> 2) & 127, pos = u >> 9;
        const float* src = feats + (((size_t)b * 128 + ci) * 16384 + (n0 + pos)) * 16 + kq * 4;
        float4v v = *(const float4v*)src;
        char* dst = smem + OFF_F + pos * 4368 + ci * 2;
        *(unsigned short*)(dst + (kq * 4 + 0) * 272) = f2bf(v[0]);
        *(unsigned short*)(dst + (kq * 4 + 1) * 272) = f2bf(v[1]);
        *(unsigned short*)(dst + (kq * 4 + 2) * 272) = f2bf(v[2]);
        *(unsigned short*)(dst + (kq * 4 + 3) * 272) = f2bf(v[3]);
    }
    if (tid < 320) {                            // 8 pos x 10 p x 4 kq
        int pos = tid / 40, r = tid % 40, p = r >> 2, kq = r & 3;
        const float* src = ppfs + (((size_t)b * 10 + p) * 16384 + (n0 + pos)) * 16 + kq * 4;
        float4v v = *(const float4v*)src;
        char* dst = smem + OFF_P + pos * 1296 + p * 2;
        *(unsigned short*)(dst + (kq * 4 + 0) * 80) = f2bf(v[0]);
        *(unsigned short*)(dst + (kq * 4 + 1) * 80) = f2bf(v[1]);
        *(unsigned short*)(dst + (kq * 4 + 2) * 80) = f2bf(v[2]);
        *(unsigned short*)(dst + (kq * 4 + 3) * 80) = f2bf(v[3]);
    } else {                                    // zero p = 10..31
        for (int z = tid - 320; z < 2816; z += 192) {
            int pos = z / 352, r = z % 352, p = 10 + (r >> 4), k2 = r & 15;
            *(unsigned short*)(smem + OFF_P + pos * 1296 + k2 * 80 + p * 2) = 0;
        }
    }
    __syncthreads();

    // ---------------- Phase 1: conv0 -> relu -> XN (+ identity column XC) ---
    {
        const int mtp = W & 3, posh = W >> 2;   // wave: 2 m-tiles x 4 positions
        bf16x8 af[2][4];
        float bias[2][4];
        for (int m = 0; m < 2; ++m) {
            int row = (2 * mtp + m) * 16 + kk;
            for (int kt = 0; kt < 4; ++kt) af[m][kt] = ldw_bf8(w0 + row * 128 + kt * 32 + 8 * g);
            for (int r = 0; r < 4; ++r) bias[m][r] = b0[(2 * mtp + m) * 16 + 4 * g + r];
        }
        for (int pp = 0; pp < 4; ++pp) {
            int pos = posh * 4 + pp;
            f32x4 acc[2] = {{0.f, 0.f, 0.f, 0.f}, {0.f, 0.f, 0.f, 0.f}};
            for (int kt = 0; kt < 4; ++kt) {
                bf16x8 bf = *(const bf16x8*)(smem + OFF_F + pos * 4368 + kk * 272 + (kt * 32 + 8 * g) * 2);
                acc[0] = MFMA(af[0][kt], bf, acc[0]);
                acc[1] = MFMA(af[1][kt], bf, acc[1]);
            }
            for (int m = 0; m < 2; ++m)
                for (int r = 0; r < 4; ++r) {
                    int c = (2 * mtp + m) * 16 + 4 * g + r;
                    float v = fmaxf(acc[m][r] + bias[m][r], 0.f);
                    unsigned short bv = f2bf(v);
                    *(unsigned short*)(smem + OFF_XN + pos * 4368 + kk * 272 + c * 2) = bv;
                    if (kk == 0) *(unsigned short*)(smem + OFF_XC + pos * 272 + c * 2) = bv;
                }
        }
    }
    __syncthreads();

    // ---------------- Phase 2: pt1 (waves 0-3) | conv1 (waves 4-7) ----------
    if (W < 4) {   // H1 = relu(pt1_w @ P), K padded 10->32 with zeros
        int mtd = W & 1, posh2 = W >> 1;
        bf16x8 af[2];
        for (int m = 0; m < 2; ++m) {
            int row = (2 * mtd + m) * 16 + kk;
            for (int j = 0; j < 8; ++j) {
                int p = 8 * g + j;
                af[m][j] = (short)((p < 10) ? f2bf(p1[row * 10 + p]) : (unsigned short)0);
            }
        }
        for (int pp = 0; pp < 4; ++pp) {
            int pos = posh2 * 4 + pp;
            bf16x8 bf = *(const bf16x8*)(smem + OFF_P + pos * 1296 + kk * 80 + (8 * g) * 2);
            for (int m = 0; m < 2; ++m) {
                f32x4 acc = {0.f, 0.f, 0.f, 0.f};
                acc = MFMA(af[m], bf, acc);
                for (int r = 0; r < 4; ++r) {
                    int mm = (2 * mtd + m) * 16 + 4 * g + r;
                    *(unsigned short*)(smem + OFF_H1 + pos * 2304 + kk * 144 + mm * 2) =
                        f2bf(fmaxf(acc[r], 0.f));
                }
            }
        }
    } else {       // x1 = conv1_w @ xn[:, k=0] + b1  (cols = positions)
        int mt = W - 4;
        int pc = kk & 7;    // clamp col->pos, cols 8..15 are discarded
        f32x4 acc = {0.f, 0.f, 0.f, 0.f};
        for (int kt = 0; kt < 4; ++kt) {
            bf16x8 bf = *(const bf16x8*)(smem + OFF_XN + pc * 4368 + (kt * 32 + 8 * g) * 2);
            bf16x8 af = ldw_bf8(w1 + (mt * 16 + kk) * 128 + kt * 32 + 8 * g);
            acc = MFMA(af, bf, acc);
        }
        if (kk < 8) {
            for (int r = 0; r < 4; ++r) {
                int m = mt * 16 + 4 * g + r;
                *(float*)(smem + OFF_X1 + kk * 256 + m * 4) = acc[r] + b1[m];
            }
        }
    }
    __syncthreads();

    // ---------------- Phase 3: pt2 (waves 0-3) | conv2 (waves 4-7) ----------
    if (W < 4) {   // PTF = pt2_w @ H1 (no bias, no relu)
        int mtd = W & 1, posh2 = W >> 1;
        bf16x8 af[2][2];
        for (int m = 0; m < 2; ++m)
            for (int kt = 0; kt < 2; ++kt)
                af[m][kt] = ldw_bf8(p2 + ((2 * mtd + m) * 16 + kk) * 64 + kt * 32 + 8 * g);
        for (int pp = 0; pp < 4; ++pp) {
            int pos = posh2 * 4 + pp;
            f32x4 acc[2] = {{0.f, 0.f, 0.f, 0.f}, {0.f, 0.f, 0.f, 0.f}};
            for (int kt = 0; kt < 2; ++kt) {
                bf16x8 bf = *(const bf16x8*)(smem + OFF_H1 + pos * 2304 + kk * 144 + (kt * 32 + 8 * g) * 2);
                acc[0] = MFMA(af[0][kt], bf, acc[0]);
                acc[1] = MFMA(af[1][kt], bf, acc[1]);
            }
            for (int m = 0; m < 2; ++m)
                for (int r = 0; r < 4; ++r) {
                    int mm = (2 * mtd + m) * 16 + 4 * g + r;
                    *(unsigned short*)(smem + OFF_PTF + pos * 2304 + kk * 144 + mm * 2) = f2bf(acc[m][r]);
                }
        }
    } else {       // X2 = conv2_w @ xn + b2
        int mtd = (W - 4) & 1, posh2 = (W - 4) >> 1;
        bf16x8 af[2][4];
        float bias[2][4];
        for (int m = 0; m < 2; ++m) {
            int base = (2 * mtd + m) * 16;
            for (int kt = 0; kt < 4; ++kt) af[m][kt] = ldw_bf8(w2 + (base + kk) * 128 + kt * 32 + 8 * g);
            for (int r = 0; r < 4; ++r) bias[m][r] = b2[base + 4 * g + r];
        }
        for (int pp = 0; pp < 4; ++pp) {
            int pos = posh2 * 4 + pp;
            f32x4 acc[2] = {{0.f, 0.f, 0.f, 0.f}, {0.f, 0.f, 0.f, 0.f}};
            for (int kt = 0; kt < 4; ++kt) {
                bf16x8 bf = *(const bf16x8*)(smem + OFF_XN + pos * 4368 + kk * 272 + (kt * 32 + 8 * g) * 2);
                acc[0] = MFMA(af[0][kt], bf, acc[0]);
                acc[1] = MFMA(af[1][kt], bf, acc[1]);
            }
            for (int m = 0; m < 2; ++m)
                for (int r = 0; r < 4; ++r) {
                    int mm = (2 * mtd + m) * 16 + 4 * g + r;
                    *(unsigned short*)(smem + OFF_X2 + pos * 2304 + kk * 144 + mm * 2) =
                        f2bf(acc[m][r] + bias[m][r]);
                }
        }
    }
    __syncthreads();

    // ---------------- Phase 4: conv3 + combine -> X3, XFS -------------------
    {
        int mtd = W & 1, posq = W >> 1;   // 2 m-tiles x 2 positions per wave
        bf16x8 af[2][4];
        float bias[2][4];
        for (int m = 0; m < 2; ++m) {
            int base = (2 * mtd + m) * 16;
            for (int kt = 0; kt < 4; ++kt) af[m][kt] = ldw_bf8(w3 + (base + kk) * 128 + kt * 32 + 8 * g);
            for (int r = 0; r < 4; ++r) bias[m][r] = b3[base + 4 * g + r];
        }
        for (int pp = 0; pp < 2; ++pp) {
            int pos = posq * 2 + pp;
            f32x4 acc[2] = {{0.f, 0.f, 0.f, 0.f}, {0.f, 0.f, 0.f, 0.f}};
            for (int kt = 0; kt < 4; ++kt) {
                bf16x8 bf = *(const bf16x8*)(smem + OFF_XN + pos * 4368 + kk * 272 + (kt * 32 + 8 * g) * 2);
                acc[0] = MFMA(af[0][kt], bf, acc[0]);
                acc[1] = MFMA(af[1][kt], bf, acc[1]);
            }
            for (int m = 0; m < 2; ++m)
                for (int r = 0; r < 4; ++r) {
                    int mm = (2 * mtd + m) * 16 + 4 * g + r;
                    float ptf = bf2f(*(const unsigned short*)(smem + OFF_PTF + pos * 2304 + kk * 144 + mm * 2));
                    float x2v = bf2f(*(const unsigned short*)(smem + OFF_X2 + pos * 2304 + kk * 144 + mm * 2));
                    float x1v = *(const float*)(smem + OFF_X1 + pos * 256 + mm * 4);
                    float x3v = acc[m][r] + bias[m][r] + ptf;
                    float xfs = x1v - x2v + ptf;
                    int cp = mm * 16 + kk;   // c' = m*K + k flattening
                    *(unsigned short*)(smem + OFF_X3 + pos * 2064 + cp * 2) = f2bf(x3v);
                    *(unsigned short*)(smem + OFF_XFS + pos * 2064 + cp * 2) = f2bf(xfs);
                }
        }
    }
    __syncthreads();

    // ---------------- Phase 5: h[j] = relu(cw1[j,:] . XFS) ------------------
    {
        int j = lane >> 3, pos = lane & 7;    // wave covers c' range [W*128, W*128+128)
        const float* wrow = cw1 + j * 1024 + W * 128;
        float s = 0.f;
        for (int cc = 0; cc < 128; cc += 4) {
            ushort4v xv = *(const ushort4v*)(smem + OFF_XFS + pos * 2064 + (W * 128 + cc) * 2);
            float4v wv = *(const float4v*)(wrow + cc);
            s += wv[0] * bf2f(xv[0]) + wv[1] * bf2f(xv[1]) +
                 wv[2] * bf2f(xv[2]) + wv[3] * bf2f(xv[3]);
        }
        *(float*)(smem + OFF_HP + W * 256 + lane * 4) = s;
    }
    __syncthreads();
    if (tid < 64) {
        float s = 0.f;
        for (int ww = 0; ww < 8; ++ww) s += *(const float*)(smem + OFF_HP + ww * 256 + tid * 4);
        *(float*)(smem + OFF_HB + tid * 4) = fmaxf(s, 0.f);
    }
    __syncthreads();

    // ---------------- Phase 6: w-logits + softmax over k --------------------
    {
        int pos = W;
        for (int jj = 0; jj < 2; ++jj) {
            int j2 = g + jj * 4;
            int c = j2 * 16 + kk;
            float wl = cb2[c];
            float4v wv0 = *(const float4v*)(cw2 + c * 8);
            float4v wv1 = *(const float4v*)(cw2 + c * 8 + 4);
            for (int j = 0; j < 4; ++j) {
                wl += wv0[j] * *(const float*)(smem + OFF_HB + (j * 8 + pos) * 4);
                wl += wv1[j] * *(const float*)(smem + OFF_HB + ((j + 4) * 8 + pos) * 4);
            }
            float mx = wl;
            for (int off = 8; off >= 1; off >>= 1) mx = fmaxf(mx, __shfl_xor(mx, off, 16));
            float e = __expf(wl - mx);
            float ss = e;
            for (int off = 8; off >= 1; off >>= 1) ss += __shfl_xor(ss, off, 16);
            *(float*)(smem + OFF_WS + pos * 512 + j2 * 64 + kk * 4) = e / ss;
        }
    }
    __syncthreads();

    // ---------------- Phase 7: om[m] = relu(sum_k w[m%8,k] * X3[m,k]) -------
    {
        int pos = W, m = lane, j2 = lane & 7;
        float s = 0.f;
        for (int kq = 0; kq < 2; ++kq) {
            ushort8v xv = *(const ushort8v*)(smem + OFF_X3 + pos * 2064 + (m * 16 + kq * 8) * 2);
            for (int i = 0; i < 8; ++i)
                s += *(const float*)(smem + OFF_WS + pos * 512 + j2 * 64 + (kq * 8 + i) * 4) * bf2f(xv[i]);
        }
        *(unsigned short*)(smem + OFF_OM + pos * 144 + m * 2) = f2bf(fmaxf(s, 0.f));
    }
    __syncthreads();

    // ---------------- Phase 8: convout + bias + identity -> out -------------
    {
        int mt = W;
        int pc = kk & 7;
        f32x4 acc = {0.f, 0.f, 0.f, 0.f};
        for (int kt = 0; kt < 2; ++kt) {
            bf16x8 bf = *(const bf16x8*)(smem + OFF_OM + pc * 144 + (kt * 32 + 8 * g) * 2);
            bf16x8 af = ldw_bf8(wo + (mt * 16 + kk) * 64 + kt * 32 + 8 * g);
            acc = MFMA(af, bf, acc);
        }
        if (kk < 8) {
            int pos = kk;
            for (int r = 0; r < 4; ++r) {
                int o = mt * 16 + 4 * g + r;
                float v = acc[r] + bo[o] +
                          bf2f(*(const unsigned short*)(smem + OFF_XC + pos * 272 + o * 2));
                out[((size_t)b * 128 + o) * 16384 + n0 + pos] = v;
            }
        }
    }
}

extern "C" void kernel_launch(void* const* d_in, const int* in_sizes, int n_in,
                              void* d_out, int out_size, void* d_ws, size_t ws_size,
                              hipStream_t stream) {
    (void)in_sizes; (void)n_in; (void)out_size; (void)d_ws; (void)ws_size;
    const float* feats = (const float*)d_in[0];
    const float* ppfs  = (const float*)d_in[1];
    const float* w0  = (const float*)d_in[2];
    const float* b0  = (const float*)d_in[3];
    const float* w1  = (const float*)d_in[4];
    const float* b1  = (const float*)d_in[5];
    const float* w2  = (const float*)d_in[6];
    const float* b2  = (const float*)d_in[7];
    const float* w3  = (const float*)d_in[8];
    const float* b3  = (const float*)d_in[9];
    const float* cw1 = (const float*)d_in[10];
    const float* cw2 = (const float*)d_in[11];
    const float* cb2 = (const float*)d_in[12];
    const float* wo  = (const float*)d_in[13];
    const float* bo  = (const float*)d_in[14];
    const float* p1  = (const float*)d_in[15];
    const float* p2  = (const float*)d_in[16];
    float* out = (float*)d_out;

    // Allow >64KB dynamic LDS (ignore result; harmless if unsupported/no-op).
    (void)hipFuncSetAttribute(reinterpret_cast<const void*>(fused_model_kernel),
                              hipFuncAttributeMaxDynamicSharedMemorySize, SMEM_BYTES);

    fused_model_kernel<<<dim3(8192), dim3(512), SMEM_BYTES, stream>>>(
        feats, ppfs, w0, b0, w1, b1, w2, b2, w3, b3, cw1, cw2, cb2, wo, bo, p1, p2, out);
}